// Round 1
// baseline (260.170 us; speedup 1.0000x reference)
//
#include <hip/hip_runtime.h>

#define SS 730
#define GG 4000
#define LENF 15

// ---------------------------------------------------------------------------
// Scan kernel: one thread per (cell g, multiplier m, model). inst = tid / GG:
//   inst 0,1 -> HBV with m = inst&1 ; inst 2,3 -> EXP-HYDRO with m = inst&1.
// Each thread runs its 730-step recurrence and atomicAdds 0.25*q into qsim.
// Lanes within a wave cover consecutive g -> coalesced x loads & atomics.
// ---------------------------------------------------------------------------
__global__ __launch_bounds__(64) void hydro_scan(const float* __restrict__ x,
                                                 const float* __restrict__ raw,
                                                 float* __restrict__ qsim) {
    int tid = blockIdx.x * 64 + threadIdx.x;
    if (tid >= 4 * GG) return;
    int g = tid % GG;
    int inst = tid / GG;
    int m = inst & 1;
    const float* xp = x + (size_t)g * 3;
    const float* pr = raw + (size_t)g * 38 + m;   // pr[2*i] = raw[g, i*2+m]

    // prefetch first forcing
    float p = xp[0], tc = xp[1], pet = xp[2];

    if (inst < 2) {
        // ---- HBV parameters (descale) ----
        float beta  = 1.0f   + pr[0]  * 5.0f;
        float fc    = 50.0f  + pr[2]  * 950.0f;
        float k0    = 0.05f  + pr[4]  * 0.85f;
        float k1    = 0.01f  + pr[6]  * 0.49f;
        float k2    = 0.001f + pr[8]  * 0.199f;
        float lp    = 0.2f   + pr[10] * 0.8f;
        float perc  =          pr[12] * 10.0f;
        float uzl   =          pr[14] * 100.0f;
        float tt    = -2.5f  + pr[16] * 5.0f;
        float cfmax = 0.5f   + pr[18] * 9.5f;
        float cfr   =          pr[20] * 0.1f;
        float cwh   =          pr[22] * 0.2f;
        float invfc   = 1.0f / fc;
        float invlpfc = 1.0f / (lp * fc);
        float cfrcf   = cfr * cfmax;

        float sp = 1e-5f, mw = 1e-5f, sm = 0.5f * fc, suz = 1e-5f, slz = 1e-5f;

        for (int t = 0; t < SS; ++t) {
            // rotate-prefetch next step's forcing (hides L2/L3 latency)
            const float* xn = xp + ((t + 1 < SS) ? 3 * GG : 0);
            float pn = xn[0], tn = xn[1], petn = xn[2];

            float rain = (tc >= tt) ? p : 0.0f;
            float snow = (tc <  tt) ? p : 0.0f;
            sp += snow;
            float melt = fminf(fmaxf(cfmax * (tc - tt), 0.0f), sp);
            mw += melt; sp -= melt;
            float refr = fminf(fmaxf(cfrcf * (tt - tc), 0.0f), mw);
            sp += refr; mw -= refr;
            float tosoil = fmaxf(mw - cwh * sp, 0.0f);
            mw -= tosoil;
            // sw = clip((sm/fc)^beta, 0, 1); sm/fc in (0,1] so log2 is finite
            float sw = fminf(fmaxf(exp2f(beta * log2f(sm * invfc)), 0.0f), 1.0f);
            float rt = rain + tosoil;
            float rech = rt * sw;
            sm += rt - rech;
            float excess = fmaxf(sm - fc, 0.0f);
            sm -= excess;
            float et = fminf(pet * fminf(fmaxf(sm * invlpfc, 0.0f), 1.0f), sm);
            sm = fmaxf(sm - et, 1e-5f);
            suz += rech + excess;
            float pa = fminf(perc, suz);
            suz -= pa;
            float q0 = k0 * fmaxf(suz - uzl, 0.0f);
            suz -= q0;
            float q1 = k1 * suz;
            suz -= q1;
            slz += pa;
            float q2 = k2 * slz;
            slz -= q2;

            atomicAdd(&qsim[t * GG + g], 0.25f * (q0 + q1 + q2));

            p = pn; tc = tn; pet = petn; xp = xn;
        }
    } else {
        // ---- EXP-HYDRO parameters (descale); cols 24 + 2j + m ----
        const float* pe = pr + 24;
        float f    =           pe[0]  * 0.1f;
        float smax = 100.0f  + pe[2]  * 1400.0f;
        float qmax = 10.0f   + pe[4]  * 40.0f;
        float df   =           pe[6]  * 5.0f;
        float tmax =           pe[8]  * 3.0f;
        float tmin = -3.0f   + pe[10] * 3.0f;
        float invsmax = 1.0f / smax;

        float s0 = 1e-5f, s1 = 0.5f * smax;

        for (int t = 0; t < SS; ++t) {
            const float* xn = xp + ((t + 1 < SS) ? 3 * GG : 0);
            float pn = xn[0], tn = xn[1], petn = xn[2];

            float ps  = (tc <= tmin) ? p : 0.0f;
            float prr = p - ps;
            float melt = (tc > tmax) ? fminf(s0, df * (tc - tmax)) : 0.0f;
            s0 += ps - melt;
            s1 += prr + melt;
            float qspill = fmaxf(s1 - smax, 0.0f);
            s1 -= qspill;
            float et = fminf(pet * fminf(fmaxf(s1 * invsmax, 0.0f), 1.0f), s1);
            s1 -= et;
            float qb = fminf(qmax * expf(-f * fmaxf(smax - s1, 0.0f)), s1);
            s1 -= qb;

            atomicAdd(&qsim[t * GG + g], 0.25f * (qspill + qb));

            p = pn; tc = tn; pet = petn; xp = xn;
        }
    }
}

// ---------------------------------------------------------------------------
// Routing kernel: out[t,g] = sum_k w[k,g] * qsim[t-k,g] with normalized
// gamma-UH weights. gammaln/const terms cancel in the normalization, so
// w[k] ∝ exp((aa-1)*ln(k+0.5) - (k+0.5)/th).
// ---------------------------------------------------------------------------
__global__ __launch_bounds__(256) void hydro_route(const float* __restrict__ qsim,
                                                   const float* __restrict__ raw,
                                                   float* __restrict__ out) {
    int idx = blockIdx.x * 256 + threadIdx.x;
    if (idx >= SS * GG) return;
    int g = idx % GG;          // g fast -> coalesced
    int t = idx / GG;

    float a = raw[(size_t)g * 38 + 36] * 2.9f;
    float b = raw[(size_t)g * 38 + 37] * 6.5f;
    float aa = fmaxf(a, 0.0f) + 0.1f;
    float th = fmaxf(b, 0.0f) + 0.5f;
    float am1 = aa - 1.0f;
    float invth = 1.0f / th;

    const float logt[LENF] = {
        -0.69314718f, 0.40546511f, 0.91629073f, 1.25276297f, 1.50407740f,
         1.70474809f, 1.87180218f, 2.01490302f, 2.14006616f, 2.25129180f,
         2.35137526f, 2.44234704f, 2.52572864f, 2.60268969f, 2.67414865f };

    float w[LENF];
    float s = 0.0f;
#pragma unroll
    for (int k = 0; k < LENF; ++k) {
        float tk = (float)k + 0.5f;
        w[k] = expf(am1 * logt[k] - tk * invth);
        s += w[k];
    }
    float invs = 1.0f / s;

    float acc = 0.0f;
#pragma unroll
    for (int k = 0; k < LENF; ++k) {
        int tp = t - k;
        if (tp >= 0) acc += w[k] * qsim[tp * GG + g];
    }
    out[idx] = acc * invs;
}

// ---------------------------------------------------------------------------
extern "C" void kernel_launch(void* const* d_in, const int* in_sizes, int n_in,
                              void* d_out, int out_size, void* d_ws, size_t ws_size,
                              hipStream_t stream) {
    const float* x   = (const float*)d_in[0];   // (730, 4000, 3) f32
    const float* raw = (const float*)d_in[1];   // (4000, 38) f32
    float* out  = (float*)d_out;                // (730, 4000) f32
    float* qsim = (float*)d_ws;                 // 730*4000 f32 = 11.7 MB scratch

    hipMemsetAsync(qsim, 0, (size_t)SS * GG * sizeof(float), stream);
    hydro_scan<<<(4 * GG + 63) / 64, 64, 0, stream>>>(x, raw, qsim);
    hydro_route<<<(SS * GG + 255) / 256, 256, 0, stream>>>(qsim, raw, out);
}

// Round 2
// 138.434 us; speedup vs baseline: 1.8794x; 1.8794x over previous
//
#include <hip/hip_runtime.h>

#define SS 730
#define GG 4000
#define LENF 15
#define PD 10          // prefetch depth (steps); 730 % 10 == 0
#define GPAD 4032      // 63 waves per instance -> no wave mixes models
#define TT 10          // route time-tile; 730 % 10 == 0

// ---------------------------------------------------------------------------
// Scan kernel: one thread per (cell g, multiplier m, model).
//   inst = tid / GPAD: 0,1 -> HBV (m = inst&1); 2,3 -> EXP-HYDRO (m = inst&1).
// Deep register prefetch: forcing for step t+PD is loaded at step t via a
// PD-deep circular register buffer with static (unrolled) indices, hiding
// ~900-cycle HBM latency behind ~PD iterations of ALU work.
// ---------------------------------------------------------------------------
__global__ __launch_bounds__(64) void hydro_scan(const float* __restrict__ x,
                                                 const float* __restrict__ raw,
                                                 float* __restrict__ qsim) {
    int tid = blockIdx.x * 64 + threadIdx.x;
    int g = tid % GPAD;
    int inst = tid / GPAD;
    if (g >= GG) return;
    int m = inst & 1;
    const float* xg = x + (size_t)g * 3;
    const float* pr = raw + (size_t)g * 38 + m;   // pr[2*i] = raw[g, i*2+m]

    // prefetch pipeline: steps 0..PD-1
    float pb[PD], tb[PD], eb[PD];
#pragma unroll
    for (int j = 0; j < PD; ++j) {
        const float* xn = xg + (size_t)j * (3 * GG);
        pb[j] = xn[0]; tb[j] = xn[1]; eb[j] = xn[2];
    }

    if (inst < 2) {
        // ---- HBV parameters (descale) ----
        float beta  = 1.0f   + pr[0]  * 5.0f;
        float fc    = 50.0f  + pr[2]  * 950.0f;
        float k0    = 0.05f  + pr[4]  * 0.85f;
        float k1    = 0.01f  + pr[6]  * 0.49f;
        float k2    = 0.001f + pr[8]  * 0.199f;
        float lp    = 0.2f   + pr[10] * 0.8f;
        float perc  =          pr[12] * 10.0f;
        float uzl   =          pr[14] * 100.0f;
        float tt    = -2.5f  + pr[16] * 5.0f;
        float cfmax = 0.5f   + pr[18] * 9.5f;
        float cfr   =          pr[20] * 0.1f;
        float cwh   =          pr[22] * 0.2f;
        float invfc   = 1.0f / fc;
        float invlpfc = 1.0f / (lp * fc);
        float cfrcf   = cfr * cfmax;

        float sp = 1e-5f, mw = 1e-5f, sm = 0.5f * fc, suz = 1e-5f, slz = 1e-5f;

        for (int c = 0; c < SS / PD; ++c) {
#pragma unroll
            for (int j = 0; j < PD; ++j) {
                int t = c * PD + j;
                float p = pb[j], tc = tb[j], pet = eb[j];
                // issue prefetch for step t+PD (clamped; branchless, uniform)
                {
                    int tn = t + PD; tn = tn < SS ? tn : SS - 1;
                    const float* xn = xg + (size_t)tn * (3 * GG);
                    pb[j] = xn[0]; tb[j] = xn[1]; eb[j] = xn[2];
                }

                float rain = (tc >= tt) ? p : 0.0f;
                float snow = (tc <  tt) ? p : 0.0f;
                sp += snow;
                float melt = fminf(fmaxf(cfmax * (tc - tt), 0.0f), sp);
                mw += melt; sp -= melt;
                float refr = fminf(fmaxf(cfrcf * (tt - tc), 0.0f), mw);
                sp += refr; mw -= refr;
                float tosoil = fmaxf(mw - cwh * sp, 0.0f);
                mw -= tosoil;
                float sw = fminf(exp2f(beta * __log2f(sm * invfc)), 1.0f);
                float rt = rain + tosoil;
                float rech = rt * sw;
                sm += rt - rech;
                float excess = fmaxf(sm - fc, 0.0f);
                sm -= excess;
                float et = fminf(pet * fminf(fmaxf(sm * invlpfc, 0.0f), 1.0f), sm);
                sm = fmaxf(sm - et, 1e-5f);
                suz += rech + excess;
                float pa = fminf(perc, suz);
                suz -= pa;
                float q0 = k0 * fmaxf(suz - uzl, 0.0f);
                suz -= q0;
                float q1 = k1 * suz;
                suz -= q1;
                slz += pa;
                float q2 = k2 * slz;
                slz -= q2;

                atomicAdd(&qsim[t * GG + g], 0.25f * (q0 + q1 + q2));
            }
        }
    } else {
        // ---- EXP-HYDRO parameters (descale); cols 24 + 2j + m ----
        const float* pe = pr + 24;
        float f    =           pe[0]  * 0.1f;
        float smax = 100.0f  + pe[2]  * 1400.0f;
        float qmax = 10.0f   + pe[4]  * 40.0f;
        float df   =           pe[6]  * 5.0f;
        float tmax =           pe[8]  * 3.0f;
        float tmin = -3.0f   + pe[10] * 3.0f;
        float invsmax = 1.0f / smax;

        float s0 = 1e-5f, s1 = 0.5f * smax;

        for (int c = 0; c < SS / PD; ++c) {
#pragma unroll
            for (int j = 0; j < PD; ++j) {
                int t = c * PD + j;
                float p = pb[j], tc = tb[j], pet = eb[j];
                {
                    int tn = t + PD; tn = tn < SS ? tn : SS - 1;
                    const float* xn = xg + (size_t)tn * (3 * GG);
                    pb[j] = xn[0]; tb[j] = xn[1]; eb[j] = xn[2];
                }

                float ps  = (tc <= tmin) ? p : 0.0f;
                float prr = p - ps;
                float melt = (tc > tmax) ? fminf(s0, df * (tc - tmax)) : 0.0f;
                s0 += ps - melt;
                s1 += prr + melt;
                float qspill = fmaxf(s1 - smax, 0.0f);
                s1 -= qspill;
                float et = fminf(pet * fminf(fmaxf(s1 * invsmax, 0.0f), 1.0f), s1);
                s1 -= et;
                float qb = fminf(qmax * expf(-f * fmaxf(smax - s1, 0.0f)), s1);
                s1 -= qb;

                atomicAdd(&qsim[t * GG + g], 0.25f * (qspill + qb));
            }
        }
    }
}

// ---------------------------------------------------------------------------
// Routing kernel, t-tiled: each thread owns one g and TT consecutive t's.
// Gamma-UH weights computed ONCE per thread (gammaln cancels under the
// normalization: w[k] ∝ exp((aa-1)*ln(k+0.5) - (k+0.5)/th)).
// ---------------------------------------------------------------------------
__global__ __launch_bounds__(256) void hydro_route(const float* __restrict__ qsim,
                                                   const float* __restrict__ raw,
                                                   float* __restrict__ out) {
    int idx = blockIdx.x * 256 + threadIdx.x;
    if (idx >= GG * (SS / TT)) return;
    int g = idx % GG;          // g fast -> coalesced
    int c = idx / GG;
    int t0 = c * TT;

    float a = raw[(size_t)g * 38 + 36] * 2.9f;
    float b = raw[(size_t)g * 38 + 37] * 6.5f;
    float aa = fmaxf(a, 0.0f) + 0.1f;
    float th = fmaxf(b, 0.0f) + 0.5f;
    float am1 = aa - 1.0f;
    float invth = 1.0f / th;

    const float logt[LENF] = {
        -0.69314718f, 0.40546511f, 0.91629073f, 1.25276297f, 1.50407740f,
         1.70474809f, 1.87180218f, 2.01490302f, 2.14006616f, 2.25129180f,
         2.35137526f, 2.44234704f, 2.52572864f, 2.60268969f, 2.67414865f };

    float w[LENF];
    float s = 0.0f;
#pragma unroll
    for (int k = 0; k < LENF; ++k) {
        float tk = (float)k + 0.5f;
        w[k] = expf(am1 * logt[k] - tk * invth);
        s += w[k];
    }
    float invs = 1.0f / s;

    // load qsim[t0-14 .. t0+TT-1] (zeros before t=0)
    float v[TT + LENF - 1];
#pragma unroll
    for (int i = 0; i < TT + LENF - 1; ++i) {
        int tp = t0 - (LENF - 1) + i;
        v[i] = (tp >= 0) ? qsim[(size_t)tp * GG + g] : 0.0f;
    }
#pragma unroll
    for (int j = 0; j < TT; ++j) {
        float acc = 0.0f;
#pragma unroll
        for (int k = 0; k < LENF; ++k)
            acc += w[k] * v[j + (LENF - 1) - k];
        out[(size_t)(t0 + j) * GG + g] = acc * invs;
    }
}

// ---------------------------------------------------------------------------
extern "C" void kernel_launch(void* const* d_in, const int* in_sizes, int n_in,
                              void* d_out, int out_size, void* d_ws, size_t ws_size,
                              hipStream_t stream) {
    const float* x   = (const float*)d_in[0];   // (730, 4000, 3) f32
    const float* raw = (const float*)d_in[1];   // (4000, 38) f32
    float* out  = (float*)d_out;                // (730, 4000) f32
    float* qsim = (float*)d_ws;                 // 730*4000 f32 = 11.7 MB scratch

    hipMemsetAsync(qsim, 0, (size_t)SS * GG * sizeof(float), stream);
    hydro_scan<<<(4 * GPAD) / 64, 64, 0, stream>>>(x, raw, qsim);
    hydro_route<<<(GG * (SS / TT) + 255) / 256, 256, 0, stream>>>(qsim, raw, out);
}

// Round 3
// 125.949 us; speedup vs baseline: 2.0657x; 1.0991x over previous
//
#include <hip/hip_runtime.h>

#define SS 730
#define GG 4000
#define LENF 15
#define PD 10          // prefetch depth (steps); 730 % 10 == 0
#define GPAD 4032      // 63 waves per instance -> no wave mixes models
#define TT 10          // route time-tile; 730 % 10 == 0
#define QN ((size_t)SS * GG)

// ---------------------------------------------------------------------------
// Scan kernel: one thread per (cell g, multiplier m, model).
//   inst = tid / GPAD: 0,1 -> HBV (m = inst&1); 2,3 -> EXP-HYDRO (m = inst&1).
// STORE4 path: each instance writes its own qsim slice (no atomics, no
// cross-XCD RMW contention). Fallback path: atomicAdd into one slice.
// Deep register prefetch (PD steps ahead) hides HBM/L3 latency; last chunk
// is peeled so the main loop has no clamp on the prefetch address.
// ---------------------------------------------------------------------------
template<bool STORE4>
__global__ __launch_bounds__(64) void hydro_scan(const float* __restrict__ x,
                                                 const float* __restrict__ raw,
                                                 float* __restrict__ qsim) {
    int tid = blockIdx.x * 64 + threadIdx.x;
    int g = tid % GPAD;
    int inst = tid / GPAD;
    if (g >= GG) return;
    int m = inst & 1;
    const float* xg = x + (size_t)g * 3;
    const float* pr = raw + (size_t)g * 38 + m;   // pr[2*i] = raw[g, i*2+m]

    float* qp = qsim + (STORE4 ? (size_t)inst * QN : 0) + g;

    // prefetch pipeline: steps 0..PD-1
    float pb[PD], tb[PD], eb[PD];
#pragma unroll
    for (int j = 0; j < PD; ++j) {
        const float* xn = xg + (size_t)j * (3 * GG);
        pb[j] = xn[0]; tb[j] = xn[1]; eb[j] = xn[2];
    }

    if (inst < 2) {
        // ---- HBV parameters (descale) ----
        float beta  = 1.0f   + pr[0]  * 5.0f;
        float fc    = 50.0f  + pr[2]  * 950.0f;
        float k0    = 0.05f  + pr[4]  * 0.85f;
        float k1    = 0.01f  + pr[6]  * 0.49f;
        float k2    = 0.001f + pr[8]  * 0.199f;
        float lp    = 0.2f   + pr[10] * 0.8f;
        float perc  =          pr[12] * 10.0f;
        float uzl   =          pr[14] * 100.0f;
        float tt    = -2.5f  + pr[16] * 5.0f;
        float cfmax = 0.5f   + pr[18] * 9.5f;
        float cfr   =          pr[20] * 0.1f;
        float cwh   =          pr[22] * 0.2f;
        float invfc   = 1.0f / fc;
        float invlpfc = 1.0f / (lp * fc);
        float cfrcf   = cfr * cfmax;

        float sp = 1e-5f, mw = 1e-5f, sm = 0.5f * fc, suz = 1e-5f, slz = 1e-5f;

        auto body = [&](float p, float tc, float pet) -> float {
            float rain = (tc >= tt) ? p : 0.0f;
            float snow = (tc <  tt) ? p : 0.0f;
            sp += snow;
            float melt = fminf(fmaxf(cfmax * (tc - tt), 0.0f), sp);
            mw += melt; sp -= melt;
            float refr = fminf(fmaxf(cfrcf * (tt - tc), 0.0f), mw);
            sp += refr; mw -= refr;
            float tosoil = fmaxf(mw - cwh * sp, 0.0f);
            mw -= tosoil;
            float sw = fminf(exp2f(beta * __log2f(sm * invfc)), 1.0f);
            float rt = rain + tosoil;
            float rech = rt * sw;
            sm += rt - rech;
            float excess = fmaxf(sm - fc, 0.0f);
            sm -= excess;
            float et = fminf(pet * fminf(fmaxf(sm * invlpfc, 0.0f), 1.0f), sm);
            sm = fmaxf(sm - et, 1e-5f);
            suz += rech + excess;
            float pa = fminf(perc, suz);
            suz -= pa;
            float q0 = k0 * fmaxf(suz - uzl, 0.0f);
            suz -= q0;
            float q1 = k1 * suz;
            suz -= q1;
            slz += pa;
            float q2 = k2 * slz;
            slz -= q2;
            return q0 + q1 + q2;
        };

        const float* xpre = xg + (size_t)PD * (3 * GG);
        for (int c = 0; c < SS / PD - 1; ++c) {
#pragma unroll
            for (int j = 0; j < PD; ++j) {
                float p = pb[j], tc = tb[j], pet = eb[j];
                pb[j] = xpre[0]; tb[j] = xpre[1]; eb[j] = xpre[2];
                xpre += 3 * GG;
                float q = body(p, tc, pet);
                if (STORE4) *qp = q; else atomicAdd(qp, 0.25f * q);
                qp += GG;
            }
        }
#pragma unroll
        for (int j = 0; j < PD; ++j) {           // peeled last chunk
            float q = body(pb[j], tb[j], eb[j]);
            if (STORE4) *qp = q; else atomicAdd(qp, 0.25f * q);
            qp += GG;
        }
    } else {
        // ---- EXP-HYDRO parameters (descale); cols 24 + 2j + m ----
        const float* pe = pr + 24;
        float f    =           pe[0]  * 0.1f;
        float smax = 100.0f  + pe[2]  * 1400.0f;
        float qmax = 10.0f   + pe[4]  * 40.0f;
        float df   =           pe[6]  * 5.0f;
        float tmax =           pe[8]  * 3.0f;
        float tmin = -3.0f   + pe[10] * 3.0f;
        float invsmax = 1.0f / smax;

        float s0 = 1e-5f, s1 = 0.5f * smax;

        auto body = [&](float p, float tc, float pet) -> float {
            float ps  = (tc <= tmin) ? p : 0.0f;
            float prr = p - ps;
            float melt = (tc > tmax) ? fminf(s0, df * (tc - tmax)) : 0.0f;
            s0 += ps - melt;
            s1 += prr + melt;
            float qspill = fmaxf(s1 - smax, 0.0f);
            s1 -= qspill;
            float et = fminf(pet * fminf(fmaxf(s1 * invsmax, 0.0f), 1.0f), s1);
            s1 -= et;
            float qb = fminf(qmax * expf(-f * fmaxf(smax - s1, 0.0f)), s1);
            s1 -= qb;
            return qspill + qb;
        };

        const float* xpre = xg + (size_t)PD * (3 * GG);
        for (int c = 0; c < SS / PD - 1; ++c) {
#pragma unroll
            for (int j = 0; j < PD; ++j) {
                float p = pb[j], tc = tb[j], pet = eb[j];
                pb[j] = xpre[0]; tb[j] = xpre[1]; eb[j] = xpre[2];
                xpre += 3 * GG;
                float q = body(p, tc, pet);
                if (STORE4) *qp = q; else atomicAdd(qp, 0.25f * q);
                qp += GG;
            }
        }
#pragma unroll
        for (int j = 0; j < PD; ++j) {
            float q = body(pb[j], tb[j], eb[j]);
            if (STORE4) *qp = q; else atomicAdd(qp, 0.25f * q);
            qp += GG;
        }
    }
}

// ---------------------------------------------------------------------------
// Routing kernel, t-tiled: each thread owns one g and TT consecutive t's.
// NB=4: sums the 4 per-instance qsim slices inside the window (scale 0.25).
// Gamma-UH weights once per thread; gammaln cancels under normalization.
// ---------------------------------------------------------------------------
template<int NB>
__global__ __launch_bounds__(256) void hydro_route(const float* __restrict__ qsim,
                                                   const float* __restrict__ raw,
                                                   float* __restrict__ out) {
    int idx = blockIdx.x * 256 + threadIdx.x;
    if (idx >= GG * (SS / TT)) return;
    int g = idx % GG;          // g fast -> coalesced
    int c = idx / GG;
    int t0 = c * TT;

    float a = raw[(size_t)g * 38 + 36] * 2.9f;
    float b = raw[(size_t)g * 38 + 37] * 6.5f;
    float aa = fmaxf(a, 0.0f) + 0.1f;
    float th = fmaxf(b, 0.0f) + 0.5f;
    float am1 = aa - 1.0f;
    float invth = 1.0f / th;

    const float logt[LENF] = {
        -0.69314718f, 0.40546511f, 0.91629073f, 1.25276297f, 1.50407740f,
         1.70474809f, 1.87180218f, 2.01490302f, 2.14006616f, 2.25129180f,
         2.35137526f, 2.44234704f, 2.52572864f, 2.60268969f, 2.67414865f };

    float w[LENF];
    float s = 0.0f;
#pragma unroll
    for (int k = 0; k < LENF; ++k) {
        float tk = (float)k + 0.5f;
        w[k] = expf(am1 * logt[k] - tk * invth);
        s += w[k];
    }
    float scale = (NB == 4 ? 0.25f : 1.0f) / s;

    // load qsim[t0-14 .. t0+TT-1] (zeros before t=0), summing NB slices
    float v[TT + LENF - 1];
#pragma unroll
    for (int i = 0; i < TT + LENF - 1; ++i) {
        int tp = t0 - (LENF - 1) + i;
        float sv = 0.0f;
        if (tp >= 0) {
            const float* qb = qsim + (size_t)tp * GG + g;
            sv = qb[0];
            if (NB == 4) sv += qb[QN] + qb[2 * QN] + qb[3 * QN];
        }
        v[i] = sv;
    }
#pragma unroll
    for (int j = 0; j < TT; ++j) {
        float acc = 0.0f;
#pragma unroll
        for (int k = 0; k < LENF; ++k)
            acc += w[k] * v[j + (LENF - 1) - k];
        out[(size_t)(t0 + j) * GG + g] = acc * scale;
    }
}

// ---------------------------------------------------------------------------
extern "C" void kernel_launch(void* const* d_in, const int* in_sizes, int n_in,
                              void* d_out, int out_size, void* d_ws, size_t ws_size,
                              hipStream_t stream) {
    const float* x   = (const float*)d_in[0];   // (730, 4000, 3) f32
    const float* raw = (const float*)d_in[1];   // (4000, 38) f32
    float* out  = (float*)d_out;                // (730, 4000) f32
    float* qsim = (float*)d_ws;

    if (ws_size >= 4 * QN * sizeof(float)) {
        // store path: 4 independent slices, no atomics, no memset needed
        hydro_scan<true><<<(4 * GPAD) / 64, 64, 0, stream>>>(x, raw, qsim);
        hydro_route<4><<<(GG * (SS / TT) + 255) / 256, 256, 0, stream>>>(qsim, raw, out);
    } else {
        hipMemsetAsync(qsim, 0, QN * sizeof(float), stream);
        hydro_scan<false><<<(4 * GPAD) / 64, 64, 0, stream>>>(x, raw, qsim);
        hydro_route<1><<<(GG * (SS / TT) + 255) / 256, 256, 0, stream>>>(qsim, raw, out);
    }
}